// Round 3
// baseline (753.885 us; speedup 1.0000x reference)
//
#include <hip/hip_runtime.h>
#include <math.h>

#define B 4
#define S 2048
#define D 1024
#define H 16
#define DK 64
#define MS (B * S)   // 8192
#define GKA 2048     // split storage width: [hi | lo]

typedef short bf16x8 __attribute__((ext_vector_type(8)));
typedef float f32x4 __attribute__((ext_vector_type(4)));

__device__ __forceinline__ unsigned short f2bf(float x) {
  union { float f; unsigned u; } v; v.f = x;
  unsigned r = v.u + 0x7fff + ((v.u >> 16) & 1);  // RNE
  return (unsigned short)(r >> 16);
}
__device__ __forceinline__ float bf2f(unsigned short h) {
  union { unsigned u; float f; } v; v.u = ((unsigned)h) << 16;
  return v.f;
}
__device__ __forceinline__ void split2(float x, unsigned short& hi, unsigned short& lo) {
  hi = f2bf(x);
  lo = f2bf(x - bf2f(hi));
}

// ---------------------------------------------------------------------------
// prep: ALL input preprocessing in one launch, chunked by blockIdx.x:
//  [0,24576)      split k,v,q -> KSP,VSP,QSP  [8192][2048] ([hi|lo])
//  [24576,32768)  split wk,wv -> WKS,WVS      [1024][2048] (B^T layout)
//  [32768,36864)  split wq    -> WQA [16][1024][128] (A layout, [hi|lo] along k)
//  [36864,37888)  cast wo     -> WOB [1024][1024] plain bf16 (B^T layout)
//  [37888,38144)  zero M
// ---------------------------------------------------------------------------
__global__ __launch_bounds__(256) void prep_kernel(
    const float* __restrict__ q, const float* __restrict__ k, const float* __restrict__ v,
    const float* __restrict__ wk, const float* __restrict__ wv, const float* __restrict__ wq,
    const float* __restrict__ wo,
    unsigned short* __restrict__ KSP, unsigned short* __restrict__ VSP,
    unsigned short* __restrict__ QSP,
    unsigned short* __restrict__ WKS, unsigned short* __restrict__ WVS,
    unsigned short* __restrict__ WQA, unsigned short* __restrict__ WOB,
    float* __restrict__ M) {
  const int blk = blockIdx.x;
  const int tid = threadIdx.x;
  if (blk < 24576) {  // activation splits
    const int which = blk >> 13;
    const int bb = blk & 8191;
    const float* X = which == 0 ? k : (which == 1 ? v : q);
    unsigned short* O = which == 0 ? KSP : (which == 1 ? VSP : QSP);
    int t = bb * 256 + tid;
    int idx = t * 4;
    int m = idx >> 10, d = idx & 1023;
    float4 x = *(const float4*)&X[idx];
    union { unsigned short h[4]; ushort4 u; } uh, ul;
    split2(x.x, uh.h[0], ul.h[0]);
    split2(x.y, uh.h[1], ul.h[1]);
    split2(x.z, uh.h[2], ul.h[2]);
    split2(x.w, uh.h[3], ul.h[3]);
    *(ushort4*)&O[(size_t)m * GKA + d] = uh.u;
    *(ushort4*)&O[(size_t)m * GKA + 1024 + d] = ul.u;
  } else if (blk < 32768) {  // wk/wv splits (B^T layout)
    const int which = (blk - 24576) >> 12;
    const int bb = (blk - 24576) & 4095;
    const float* W = which == 0 ? wk : wv;
    unsigned short* O = which == 0 ? WKS : WVS;
    int t = bb * 256 + tid;
    int d = t & 1023, n = t >> 10;
    int h = n >> 6, dk = n & 63;
    float x = W[((size_t)(h << 10) + d) * 64 + dk];
    unsigned short hi, lo;
    split2(x, hi, lo);
    size_t ro = (size_t)n * GKA + d;
    O[ro] = hi;
    O[ro + 1024] = lo;
  } else if (blk < 36864) {  // wq split (A layout: [h][d][hi 64|lo 64])
    int t = (blk - 32768) * 256 + tid;  // 1M = 16*1024*64
    int kk = t & 63;
    int hd = t >> 6;  // h*1024 + d
    float x = wq[t];
    unsigned short hi, lo;
    split2(x, hi, lo);
    WQA[(size_t)hd * 128 + kk] = hi;
    WQA[(size_t)hd * 128 + 64 + kk] = lo;
  } else if (blk < 37888) {  // wo cast
    int t = (blk - 36864) * 256 + tid;
    int idx = t * 4;
    float4 x = *(const float4*)&wo[idx];
    ushort4 u;
    u.x = f2bf(x.x); u.y = f2bf(x.y); u.z = f2bf(x.z); u.w = f2bf(x.w);
    *(ushort4*)&WOB[idx] = u;
  } else {  // zero M (256 blocks * 256 threads * 4 = 262144 floats)
    int t = (blk - 37888) * 256 + tid;
    *(float4*)&M[(size_t)t * 4] = (float4){0.f, 0.f, 0.f, 0.f};
  }
}

// ---------------------------------------------------------------------------
// gemm256: templated 256xBN-tile 8-wave GEMM core with half-K read-ahead.
// NWC: waves along N (4 -> BN=256, 2 -> BN=128). NWR = 8/NWC waves along M.
// EPI: 0 = fp32 + bias store; 1 = per-head softmax -> bf16 (HB).
// KLOG: 3072 (Markidis 3-term split, strides 2048, wrap offsets) or
//       1024 (plain bf16, strides 1024, no wrap).
//
// Inner loop per K-tile (2 barriers only):
//   vmcnt(LPS or 0) ; B0 barrier           -- tile t landed & visible
//   issue ALL 2*(4+MR) ds_reads (half0 then half1, order pinned)
//   lgkmcnt(half1-count)                   -- half0 fragments ready
//   32|16 MFMA (half0)                     -- DS pipe drains half1 UNDER this
//   lgkmcnt(0) ; B1 barrier                -- all reads of buf done
//   stage(t+2) into same-parity buf        -- VMEM issue hides under...
//   32|16 MFMA (half1)
// Swizzle: idx ^= (fm&7)<<3 on read; staging source col pre-swizzled so the
// linear global_load_lds dest equals the swizzled tile (verified: 0 conflicts).
// ---------------------------------------------------------------------------
__device__ __forceinline__ void gll(const unsigned short* g, unsigned short* l) {
  __builtin_amdgcn_global_load_lds((const __attribute__((address_space(1))) void*)g,
                                   (__attribute__((address_space(3))) void*)l, 16, 0, 0);
}

template <int NWC, int EPI, int KLOG>
__global__ __launch_bounds__(512, 2) void gemm256(
    const unsigned short* __restrict__ A0, const unsigned short* __restrict__ A1,
    const unsigned short* __restrict__ Bt0, const unsigned short* __restrict__ Bt1,
    const float* __restrict__ bias0, const float* __restrict__ bias1,
    void* __restrict__ C0, void* __restrict__ C1) {
  constexpr int NWR = 8 / NWC;        // waves along M
  constexpr int MR = (256 / NWR) / 16;  // A-frags per wave (8 or 4)
  constexpr int BN = NWC * 64;        // tile N
  constexpr int AST = (KLOG == 1024) ? 1024 : 2048;  // phys K stride (A and B)
  constexpr int NKT = KLOG / 64;      // K-tiles
  constexpr int LPS = 4 + NWC;        // global_load_lds per thread per stage

  __shared__ __align__(16) unsigned short As[2][256 * 64];
  __shared__ __align__(16) unsigned short Bs[2][BN * 64];

  const int tid = threadIdx.x;
  const int lane = tid & 63;
  const int w = tid >> 6;
  const int wr = w / NWC;
  const int wc = w % NWC;
  const int fm = lane & 15;
  const int quad = lane >> 4;
  const int sx = (fm & 7) << 3;
  const size_t bm = (size_t)blockIdx.y * 256;
  const size_t bn = (size_t)blockIdx.x * BN;

  const unsigned short* A;
  const unsigned short* BT;
  const float* bias;
  if constexpr (EPI == 1) {
    const int b = blockIdx.y >> 3;  // 2048 rows per batch / 256-row tiles
    A = A0;
    BT = Bt0 + (size_t)b * D * GKA;
    bias = bias0 + (size_t)b * D;
  } else {
    A = blockIdx.z ? A1 : A0;
    BT = blockIdx.z ? Bt1 : Bt0;
    bias = blockIdx.z ? bias1 : bias0;
  }

  // staging source offsets (col pre-swizzled -> linear LDS dest = swizzled tile)
  const int srow = tid >> 3;                        // 0..63 within 64-row group
  const int scol = ((tid & 7) ^ (srow & 7)) << 3;   // swizzled col (ushorts)
  unsigned aoffs[4], boffs[NWC];
#pragma unroll
  for (int g = 0; g < 4; ++g) aoffs[g] = (unsigned)((bm + g * 64 + srow) * AST + scol);
#pragma unroll
  for (int g = 0; g < NWC; ++g) boffs[g] = (unsigned)((bn + g * 64 + srow) * AST + scol);

  // t-invariant fragment indices (ushort units, read-side swizzle applied)
  int bidx[4][2], aidx[MR][2];
#pragma unroll
  for (int j = 0; j < 4; ++j)
#pragma unroll
    for (int kk = 0; kk < 2; ++kk)
      bidx[j][kk] = ((wc * 64 + j * 16 + fm) * 64 + kk * 32 + quad * 8) ^ sx;
#pragma unroll
  for (int i = 0; i < MR; ++i)
#pragma unroll
    for (int kk = 0; kk < 2; ++kk)
      aidx[i][kk] = ((wr * (MR * 16) + i * 16 + fm) * 64 + kk * 32 + quad * 8) ^ sx;

  f32x4 acc[MR][4];
#pragma unroll
  for (int i = 0; i < MR; ++i)
#pragma unroll
    for (int j = 0; j < 4; ++j) acc[i][j] = (f32x4){0.f, 0.f, 0.f, 0.f};

  auto koff_a = [](int k0) { return (KLOG == 3072) ? (k0 < 2048 ? k0 : k0 - 2048) : k0; };
  auto koff_b = [](int k0) { return (KLOG == 3072) ? (k0 < 1024 ? k0 : k0 - 1024) : k0; };

  auto stage = [&](unsigned short* Asb, unsigned short* Bsb, int aof, int bof) {
#pragma unroll
    for (int g = 0; g < 4; ++g) gll(A + aoffs[g] + aof, Asb + g * 4096 + w * 512);
#pragma unroll
    for (int g = 0; g < NWC; ++g) gll(BT + boffs[g] + bof, Bsb + g * 4096 + w * 512);
  };

  // prologue: tiles 0 and 1 in flight (2*LPS outstanding per wave)
  stage(As[0], Bs[0], koff_a(0), koff_b(0));
  stage(As[1], Bs[1], koff_a(64), koff_b(64));

  auto tile = [&](const unsigned short* Ab, const unsigned short* Bb,
                  unsigned short* Asb, unsigned short* Bsb, int t) {
    if (t < NKT - 1) {
      if constexpr (NWC == 4) asm volatile("s_waitcnt vmcnt(8)" ::: "memory");
      else                    asm volatile("s_waitcnt vmcnt(6)" ::: "memory");
    } else {
      asm volatile("s_waitcnt vmcnt(0)" ::: "memory");
    }
    __builtin_amdgcn_s_barrier();       // B0: tile t visible to all waves
    __builtin_amdgcn_sched_barrier(0);

    bf16x8 b0f[4], a0f[MR], b1f[4], a1f[MR];
#pragma unroll
    for (int j = 0; j < 4; ++j) b0f[j] = *(const bf16x8*)&Bb[bidx[j][0]];
#pragma unroll
    for (int i = 0; i < MR; ++i) a0f[i] = *(const bf16x8*)&Ab[aidx[i][0]];
    __builtin_amdgcn_sched_barrier(0);  // pin: half0 reads first in lgkm order
#pragma unroll
    for (int j = 0; j < 4; ++j) b1f[j] = *(const bf16x8*)&Bb[bidx[j][1]];
#pragma unroll
    for (int i = 0; i < MR; ++i) a1f[i] = *(const bf16x8*)&Ab[aidx[i][1]];
    if constexpr (NWC == 4) asm volatile("s_waitcnt lgkmcnt(12)" ::: "memory");
    else                    asm volatile("s_waitcnt lgkmcnt(8)" ::: "memory");
    __builtin_amdgcn_sched_barrier(0);  // half0 ready; half1 still in DS pipe

    __builtin_amdgcn_s_setprio(1);
#pragma unroll
    for (int i = 0; i < MR; ++i)
#pragma unroll
      for (int j = 0; j < 4; ++j)
        acc[i][j] = __builtin_amdgcn_mfma_f32_16x16x32_bf16(a0f[i], b0f[j], acc[i][j], 0, 0, 0);
    __builtin_amdgcn_s_setprio(0);

    asm volatile("s_waitcnt lgkmcnt(0)" ::: "memory");  // half1 ready
    __builtin_amdgcn_sched_barrier(0);
    __builtin_amdgcn_s_barrier();       // B1: all waves done reading buf -> free
    if (t + 2 < NKT) {
      const int k0 = (t + 2) * 64;
      stage(Asb, Bsb, koff_a(k0), koff_b(k0));
    }
    __builtin_amdgcn_sched_barrier(0);  // pin half1 MFMA below stage issue

    __builtin_amdgcn_s_setprio(1);
#pragma unroll
    for (int i = 0; i < MR; ++i)
#pragma unroll
      for (int j = 0; j < 4; ++j)
        acc[i][j] = __builtin_amdgcn_mfma_f32_16x16x32_bf16(a1f[i], b1f[j], acc[i][j], 0, 0, 0);
    __builtin_amdgcn_s_setprio(0);
  };

#pragma unroll 1
  for (int tp = 0; tp < NKT / 2; ++tp) {
    tile(As[0], Bs[0], As[0], Bs[0], 2 * tp);
    tile(As[1], Bs[1], As[1], Bs[1], 2 * tp + 1);
  }

  if constexpr (EPI == 0) {
    float* C = (float*)(blockIdx.z ? C1 : C0);
#pragma unroll
    for (int i = 0; i < MR; ++i)
#pragma unroll
      for (int j = 0; j < 4; ++j) {
        size_t row = bm + wr * (MR * 16) + i * 16 + quad * 4;
        size_t col = bn + wc * 64 + j * 16 + fm;
        float bb = bias[col];
#pragma unroll
        for (int r = 0; r < 4; ++r) C[(row + r) * D + col] = acc[i][j][r] + bb;
      }
  } else {
    // softmax over this wave's 64 cols (= one full head), bf16 out
    unsigned short* HB = (unsigned short*)C0;
    const size_t head_col0 = bn + wc * 64;
    float bj[4];
#pragma unroll
    for (int j = 0; j < 4; ++j) bj[j] = bias[head_col0 + j * 16 + fm];
#pragma unroll
    for (int i = 0; i < MR; ++i) {
      f32x4 val[4];
#pragma unroll
      for (int j = 0; j < 4; ++j)
#pragma unroll
        for (int r = 0; r < 4; ++r) val[j][r] = (acc[i][j][r] + bj[j]) * 0.125f;

      f32x4 mx = val[0];
#pragma unroll
      for (int j = 1; j < 4; ++j)
#pragma unroll
        for (int r = 0; r < 4; ++r) mx[r] = fmaxf(mx[r], val[j][r]);
#pragma unroll
      for (int off = 1; off < 16; off <<= 1)
#pragma unroll
        for (int r = 0; r < 4; ++r) mx[r] = fmaxf(mx[r], __shfl_xor(mx[r], off, 64));

      f32x4 e[4];
      f32x4 sm = (f32x4){0.f, 0.f, 0.f, 0.f};
#pragma unroll
      for (int j = 0; j < 4; ++j)
#pragma unroll
        for (int r = 0; r < 4; ++r) {
          e[j][r] = __expf(val[j][r] - mx[r]);
          sm[r] += e[j][r];
        }
#pragma unroll
      for (int off = 1; off < 16; off <<= 1)
#pragma unroll
        for (int r = 0; r < 4; ++r) sm[r] += __shfl_xor(sm[r], off, 64);

      f32x4 inv;
#pragma unroll
      for (int r = 0; r < 4; ++r) inv[r] = 1.0f / sm[r];

#pragma unroll
      for (int j = 0; j < 4; ++j)
#pragma unroll
        for (int r = 0; r < 4; ++r) {
          size_t row = bm + wr * (MR * 16) + i * 16 + quad * 4 + r;
          HB[row * D + head_col0 + j * 16 + fm] = f2bf(e[j][r] * inv[r]);
        }
    }
  }
}

// ---------------------------------------------------------------------------
// M[b,h] = kh^T @ vh (64x64 per (b,h)), s-split 8-way with atomics.
// ---------------------------------------------------------------------------
__global__ __launch_bounds__(256) void compute_m_kernel(
    const float* __restrict__ KH, const float* __restrict__ VH, float* __restrict__ Mout) {
  const int sc = blockIdx.x, h = blockIdx.y, b = blockIdx.z;
  const int tid = threadIdx.x;
  const int i0 = (tid >> 4) * 4;
  const int j0 = (tid & 15) * 4;
  __shared__ float ks[16][64], vs[16][64];
  float acc[4][4];
#pragma unroll
  for (int a = 0; a < 4; a++)
#pragma unroll
    for (int c = 0; c < 4; c++) acc[a][c] = 0.f;

  const int s0 = sc * (S / 8);
  const int rr = tid >> 4;
  const int cc = (tid & 15) * 4;
  for (int s = s0; s < s0 + S / 8; s += 16) {
    size_t base = ((size_t)b * S + s + rr) * D + h * 64 + cc;
    __syncthreads();
    *(float4*)&ks[rr][cc] = *(const float4*)&KH[base];
    *(float4*)&vs[rr][cc] = *(const float4*)&VH[base];
    __syncthreads();
#pragma unroll
    for (int ss = 0; ss < 16; ss++) {
      float4 kf = *(const float4*)&ks[ss][i0];
      float4 vf = *(const float4*)&vs[ss][j0];
      float ka[4] = {kf.x, kf.y, kf.z, kf.w};
      float va[4] = {vf.x, vf.y, vf.z, vf.w};
#pragma unroll
      for (int a = 0; a < 4; a++)
#pragma unroll
        for (int c = 0; c < 4; c++) acc[a][c] += ka[a] * va[c];
    }
  }
  float* Mp = Mout + ((size_t)(b * H + h)) * DK * DK;
#pragma unroll
  for (int a = 0; a < 4; a++)
#pragma unroll
    for (int c = 0; c < 4; c++) atomicAdd(&Mp[(i0 + a) * DK + j0 + c], acc[a][c]);
}

// ---------------------------------------------------------------------------
// split_m_bias: M fp32 [bh][64k][64n] -> MSP bf16 [bh][2][64n][64k] (transposed
// hi,lo) AND BQM[bh][64 j] = sum_k bq[h,k]*M[k,j]  (unscaled).
// ---------------------------------------------------------------------------
__global__ __launch_bounds__(256) void split_m_bias_kernel(
    const float* __restrict__ M, const float* __restrict__ bq,
    unsigned short* __restrict__ MSP, float* __restrict__ BQM) {
  const int bh = blockIdx.x;
  const int h = bh & 15;
  const float* Mp = M + (size_t)bh * 4096;
  unsigned short* hiP = MSP + (size_t)bh * 8192;
  unsigned short* loP = hiP + 4096;
  for (int idx = threadIdx.x; idx < 4096; idx += 256) {
    int kk = idx >> 6, nn = idx & 63;
    unsigned short hi, lo;
    split2(Mp[idx], hi, lo);
    hiP[nn * 64 + kk] = hi;
    loP[nn * 64 + kk] = lo;
  }
  if (threadIdx.x < 64) {
    int j = threadIdx.x;
    float a = 0.f;
#pragma unroll 8
    for (int kk = 0; kk < 64; kk++) a += bq[h * 64 + kk] * Mp[kk * 64 + j];
    BQM[(size_t)bh * 64 + j] = a;
  }
}

// ---------------------------------------------------------------------------
// wqm: Wq'[b,h] = Wq[h] @ M[b,h]  (1024x64 per pair), 3-term split MFMA.
// A = WQA [h][1024 d][hi64|lo64]; B = MSP [bh][2][64 n][64 k] (transposed).
// Output WQM [b][n=h*64+j][d hi | 1024+d lo] (B^T layout for the qsm GEMM).
// grid (16, H, B); block = 64 d-rows; wave w owns d-rows [c*64+w*16, +16).
// ---------------------------------------------------------------------------
__global__ __launch_bounds__(256) void wqm_kernel(
    const unsigned short* __restrict__ WQA, const unsigned short* __restrict__ MSP,
    unsigned short* __restrict__ WQM) {
  const int c = blockIdx.x, h = blockIdx.y, b = blockIdx.z;
  const int tid = threadIdx.x;
  const int lane = tid & 63;
  const int w = tid >> 6;
  const int fm = lane & 15;
  const int quad = lane >> 4;
  const int ko = quad * 8;
  const int dbase = c * 64 + w * 16;

  const unsigned short* arow = WQA + ((size_t)h * 1024 + dbase + fm) * 128;
  bf16x8 ahi0 = *(const bf16x8*)&arow[ko];        // k 0..31 hi
  bf16x8 ahi1 = *(const bf16x8*)&arow[32 + ko];   // k 32..63 hi
  bf16x8 alo0 = *(const bf16x8*)&arow[64 + ko];   // k 0..31 lo
  bf16x8 alo1 = *(const bf16x8*)&arow[96 + ko];   // k 32..63 lo

  const unsigned short* hiP = MSP + ((size_t)(b * H + h)) * 8192;
  const unsigned short* loP = hiP + 4096;
  f32x4 acc[4];
#pragma unroll
  for (int j = 0; j < 4; j++) acc[j] = (f32x4){0.f, 0.f, 0.f, 0.f};
#pragma unroll
  for (int j = 0; j < 4; j++) {
    bf16x8 bhi0 = *(const bf16x8*)&hiP[(j * 16 + fm) * 64 + ko];
    bf16x8 bhi1 = *(const bf16x8*)&hiP[(j * 16 + fm) * 64 + 32 + ko];
    bf16x8 blo0 = *(const bf16x8*)&loP[(j * 16 + fm) * 64 + ko];
    bf16x8 blo1 = *(const bf16x8*)&loP[(j * 16 + fm) * 64 + 32 + ko];
    acc[j] = __builtin_amdgcn_mfma_f32_16x16x32_bf16(ahi0, bhi0, acc[j], 0, 0, 0);
    acc[j] = __builtin_amdgcn_mfma_f32_16x16x32_bf16(ahi1, bhi1, acc[j], 0, 0, 0);
    acc[j] = __builtin_amdgcn_mfma_f32_16x16x32_bf16(alo0, bhi0, acc[j], 0, 0, 0);
    acc[j] = __builtin_amdgcn_mfma_f32_16x16x32_bf16(alo1, bhi1, acc[j], 0, 0, 0);
    acc[j] = __builtin_amdgcn_mfma_f32_16x16x32_bf16(ahi0, blo0, acc[j], 0, 0, 0);
    acc[j] = __builtin_amdgcn_mfma_f32_16x16x32_bf16(ahi1, blo1, acc[j], 0, 0, 0);
  }

  // C[d=dbase+quad*4+r][col j*16+fm]; write split to WQM[b][h*64+col][d]
#pragma unroll
  for (int j = 0; j < 4; j++) {
    int n = h * 64 + j * 16 + fm;
    ushort4 hv, lv;
    unsigned short hi, lo;
    split2(acc[j][0], hi, lo); hv.x = hi; lv.x = lo;
    split2(acc[j][1], hi, lo); hv.y = hi; lv.y = lo;
    split2(acc[j][2], hi, lo); hv.z = hi; lv.z = lo;
    split2(acc[j][3], hi, lo); hv.w = hi; lv.w = lo;
    size_t base = ((size_t)b * D + n) * GKA + dbase + quad * 4;
    *(ushort4*)&WQM[base] = hv;
    *(ushort4*)&WQM[base + 1024] = lv;
  }
}

// ---------------------------------------------------------------------------
extern "C" void kernel_launch(void* const* d_in, const int* in_sizes, int n_in,
                              void* d_out, int out_size, void* d_ws, size_t ws_size,
                              hipStream_t stream) {
  const float* q = (const float*)d_in[0];
  const float* k = (const float*)d_in[1];
  const float* v = (const float*)d_in[2];
  const float* wq_w = (const float*)d_in[3];
  const float* wq_b = (const float*)d_in[4];
  const float* wk_w = (const float*)d_in[5];
  const float* wk_b = (const float*)d_in[6];
  const float* wv_w = (const float*)d_in[7];
  const float* wv_b = (const float*)d_in[8];
  const float* wo_w = (const float*)d_in[9];
  const float* wo_b = (const float*)d_in[10];
  float* out = (float*)d_out;

  // ws (143 MB): KSP 32 (->HB 16 | WQM 16) | VSP 32 (->MSP 1 + BQM) | QSP 32 |
  //              VH 32 | M 1 | WKS 4 | WVS 4 | WQA 4 | WOB 2.   KH lives in d_out.
  unsigned short* KSP = (unsigned short*)d_ws;
  unsigned short* VSP = KSP + (size_t)16 * 1024 * 1024;
  unsigned short* QSP = VSP + (size_t)16 * 1024 * 1024;
  float* VH = (float*)(QSP + (size_t)16 * 1024 * 1024);
  float* M = VH + (size_t)MS * D;
  unsigned short* WKS = (unsigned short*)(M + 256 * 1024);
  unsigned short* WVS = WKS + (size_t)2 * 1024 * 1024;
  unsigned short* WQA = WVS + (size_t)2 * 1024 * 1024;
  unsigned short* WOB = WQA + (size_t)2 * 1024 * 1024;
  // aliases
  float* KH = out;                                   // dead after compute_m
  unsigned short* HB = KSP;                          // KSP dead after gemm KV
  unsigned short* WQM = KSP + (size_t)8 * 1024 * 1024;
  unsigned short* MSP = VSP;                         // VSP dead after gemm KV
  float* BQM = (float*)(VSP + 512 * 1024);

  dim3 blk(256);

  prep_kernel<<<38144, blk, 0, stream>>>(q, k, v, wk_w, wv_w, wq_w, wo_w,
                                         KSP, VSP, QSP, WKS, WVS, WQA, WOB, M);
  // K/V projections: 256x256 tiles, split-Markidis K=3072
  gemm256<4, 0, 3072><<<dim3(4, 32, 2), dim3(512), 0, stream>>>(
      KSP, VSP, WKS, WVS, wk_b, wv_b, KH, VH);
  compute_m_kernel<<<dim3(8, H, B), blk, 0, stream>>>(KH, VH, M);
  split_m_bias_kernel<<<64, blk, 0, stream>>>(M, wq_b, MSP, BQM);
  wqm_kernel<<<dim3(16, H, B), blk, 0, stream>>>(WQA, MSP, WQM);
  // fused logit GEMM + softmax: 256x128 tiles (full 256-block grid)
  gemm256<2, 1, 3072><<<dim3(8, 32, 1), dim3(512), 0, stream>>>(
      QSP, nullptr, WQM, nullptr, BQM, nullptr, HB, nullptr);
  // output projection: plain bf16, K=1024, 256x128 tiles
  gemm256<2, 0, 1024><<<dim3(8, 32, 1), dim3(512), 0, stream>>>(
      HB, HB, WOB, WOB, wo_b, wo_b, out, out);
}

// Round 4
// 437.471 us; speedup vs baseline: 1.7233x; 1.7233x over previous
//
#include <hip/hip_runtime.h>
#include <math.h>

#define B 4
#define S 2048
#define D 1024
#define H 16
#define DK 64
#define MS (B * S)   // 8192
#define GKA 2048     // split storage width: [hi | lo]

typedef short bf16x8 __attribute__((ext_vector_type(8)));
typedef float f32x4 __attribute__((ext_vector_type(4)));

__device__ __forceinline__ unsigned short f2bf(float x) {
  union { float f; unsigned u; } v; v.f = x;
  unsigned r = v.u + 0x7fff + ((v.u >> 16) & 1);  // RNE
  return (unsigned short)(r >> 16);
}
__device__ __forceinline__ float bf2f(unsigned short h) {
  union { unsigned u; float f; } v; v.u = ((unsigned)h) << 16;
  return v.f;
}
__device__ __forceinline__ void split2(float x, unsigned short& hi, unsigned short& lo) {
  hi = f2bf(x);
  lo = f2bf(x - bf2f(hi));
}

// ---------------------------------------------------------------------------
// prep: ALL input preprocessing in one launch, chunked by blockIdx.x:
//  [0,24576)      split k,v,q -> KSP,VSP,QSP  [8192][2048] ([hi|lo])
//  [24576,32768)  split wk,wv -> WKS,WVS      [1024][2048] (B^T layout)
//  [32768,36864)  split wq    -> WQA [16][1024][128] (A layout, [hi|lo] along k)
//  [36864,37888)  cast wo     -> WOB [1024][1024] plain bf16 (B^T layout)
//  [37888,38144)  zero M
// ---------------------------------------------------------------------------
__global__ __launch_bounds__(256) void prep_kernel(
    const float* __restrict__ q, const float* __restrict__ k, const float* __restrict__ v,
    const float* __restrict__ wk, const float* __restrict__ wv, const float* __restrict__ wq,
    const float* __restrict__ wo,
    unsigned short* __restrict__ KSP, unsigned short* __restrict__ VSP,
    unsigned short* __restrict__ QSP,
    unsigned short* __restrict__ WKS, unsigned short* __restrict__ WVS,
    unsigned short* __restrict__ WQA, unsigned short* __restrict__ WOB,
    float* __restrict__ M) {
  const int blk = blockIdx.x;
  const int tid = threadIdx.x;
  if (blk < 24576) {  // activation splits
    const int which = blk >> 13;
    const int bb = blk & 8191;
    const float* X = which == 0 ? k : (which == 1 ? v : q);
    unsigned short* O = which == 0 ? KSP : (which == 1 ? VSP : QSP);
    int t = bb * 256 + tid;
    int idx = t * 4;
    int m = idx >> 10, d = idx & 1023;
    float4 x = *(const float4*)&X[idx];
    union { unsigned short h[4]; ushort4 u; } uh, ul;
    split2(x.x, uh.h[0], ul.h[0]);
    split2(x.y, uh.h[1], ul.h[1]);
    split2(x.z, uh.h[2], ul.h[2]);
    split2(x.w, uh.h[3], ul.h[3]);
    *(ushort4*)&O[(size_t)m * GKA + d] = uh.u;
    *(ushort4*)&O[(size_t)m * GKA + 1024 + d] = ul.u;
  } else if (blk < 32768) {  // wk/wv splits (B^T layout)
    const int which = (blk - 24576) >> 12;
    const int bb = (blk - 24576) & 4095;
    const float* W = which == 0 ? wk : wv;
    unsigned short* O = which == 0 ? WKS : WVS;
    int t = bb * 256 + tid;
    int d = t & 1023, n = t >> 10;
    int h = n >> 6, dk = n & 63;
    float x = W[((size_t)(h << 10) + d) * 64 + dk];
    unsigned short hi, lo;
    split2(x, hi, lo);
    size_t ro = (size_t)n * GKA + d;
    O[ro] = hi;
    O[ro + 1024] = lo;
  } else if (blk < 36864) {  // wq split (A layout: [h][d][hi 64|lo 64])
    int t = (blk - 32768) * 256 + tid;  // 1M = 16*1024*64
    int kk = t & 63;
    int hd = t >> 6;  // h*1024 + d
    float x = wq[t];
    unsigned short hi, lo;
    split2(x, hi, lo);
    WQA[(size_t)hd * 128 + kk] = hi;
    WQA[(size_t)hd * 128 + 64 + kk] = lo;
  } else if (blk < 37888) {  // wo cast
    int t = (blk - 36864) * 256 + tid;
    int idx = t * 4;
    float4 x = *(const float4*)&wo[idx];
    ushort4 u;
    u.x = f2bf(x.x); u.y = f2bf(x.y); u.z = f2bf(x.z); u.w = f2bf(x.w);
    *(ushort4*)&WOB[idx] = u;
  } else {  // zero M (256 blocks * 256 threads * 4 = 262144 floats)
    int t = (blk - 37888) * 256 + tid;
    *(float4*)&M[(size_t)t * 4] = (float4){0.f, 0.f, 0.f, 0.f};
  }
}

// ---------------------------------------------------------------------------
// gemm256: templated 256xBN-tile 8-wave GEMM core, phase-level A-prefetch.
// NWC: waves along N (4 -> BN=256, 2 -> BN=128). NWR = 8/NWC waves along M.
// EPI: 0 = fp32 + bias store; 1 = per-head softmax -> bf16.
// KLOG: 3072 (Markidis 3-term split, stride 2048, wrap) or 1024 (plain bf16).
//
// Per K-tile (2 barriers):
//   vmcnt(LPS|0) ; B0 barrier              -- tile t landed & visible
//   read bfr (8, full tile) + afr[ph0] (4)
//   for qq in 0..NPH-1:
//     issue afr[qq+1] reads (4)            -- drains in DS pipe UNDER MFMA
//     lgkmcnt(4 | 0) ; sched_barrier
//     16 MFMA (rows 2qq..2qq+1 x K=64)
//   lgkm(0) reached at last phase ; B1 barrier -- buf free
//   stage(t+2) into same-parity buf
// Register budget (NWC=4): acc 128 + bfr 32 + afr 2x16 + addr ~25 ≈ 220 < 256
// (1 block/CU from LDS 128K; launch_bounds(512,2) = 2 waves/EU = 256-reg cap).
// Swizzle: idx ^= (fm&7)<<3 on read; staging source col pre-swizzled so the
// linear global_load_lds dest equals the swizzled tile (verified 0 conflicts).
// ---------------------------------------------------------------------------
__device__ __forceinline__ void gll(const unsigned short* g, unsigned short* l) {
  __builtin_amdgcn_global_load_lds((const __attribute__((address_space(1))) void*)g,
                                   (__attribute__((address_space(3))) void*)l, 16, 0, 0);
}

template <int NWC>
__device__ __forceinline__ void stageT(
    const unsigned short* __restrict__ A, const unsigned short* __restrict__ BT,
    const unsigned* aoffs, const unsigned* boffs,
    unsigned short* Asb, unsigned short* Bsb, int aof, int bof, int w) {
#pragma unroll
  for (int g = 0; g < 4; ++g) gll(A + aoffs[g] + aof, Asb + g * 4096 + w * 512);
#pragma unroll
  for (int g = 0; g < NWC; ++g) gll(BT + boffs[g] + bof, Bsb + g * 4096 + w * 512);
}

template <int NWC, int EPI, int KLOG>
__global__ __launch_bounds__(512, 2) void gemm256(
    const unsigned short* __restrict__ A0, const unsigned short* __restrict__ A1,
    const unsigned short* __restrict__ Bt0, const unsigned short* __restrict__ Bt1,
    const float* __restrict__ bias0, const float* __restrict__ bias1,
    void* __restrict__ C0, void* __restrict__ C1) {
  constexpr int NWR = 8 / NWC;          // waves along M
  constexpr int MR = (256 / NWR) / 16;  // A-frags per wave (8 or 4)
  constexpr int NPH = MR / 2;           // phases per tile (4 or 2)
  constexpr int BN = NWC * 64;          // tile N
  constexpr int AST = (KLOG == 1024) ? 1024 : 2048;
  constexpr int NKT = KLOG / 64;        // K-tiles
  constexpr int LPS = 4 + NWC;          // global_load_lds per thread per stage

  __shared__ __align__(16) unsigned short As[2][256 * 64];
  __shared__ __align__(16) unsigned short Bs[2][BN * 64];

  const int tid = threadIdx.x;
  const int lane = tid & 63;
  const int w = tid >> 6;
  const int wr = w / NWC;
  const int wc = w % NWC;
  const int fm = lane & 15;
  const int quad = lane >> 4;
  const int sx = (fm & 7) << 3;
  const size_t bm = (size_t)blockIdx.y * 256;
  const size_t bn = (size_t)blockIdx.x * BN;

  const unsigned short* A;
  const unsigned short* BT;
  const float* bias;
  if constexpr (EPI == 1) {
    const int b = blockIdx.y >> 3;  // 2048 rows per batch / 256-row tiles
    A = A0;
    BT = Bt0 + (size_t)b * D * GKA;
    bias = bias0 + (size_t)b * D;
  } else {
    A = blockIdx.z ? A1 : A0;
    BT = blockIdx.z ? Bt1 : Bt0;
    bias = blockIdx.z ? bias1 : bias0;
  }

  // staging source offsets (col pre-swizzled -> linear LDS dest = swizzled tile)
  const int srow = tid >> 3;                        // 0..63 within 64-row group
  const int scol = ((tid & 7) ^ (srow & 7)) << 3;   // swizzled col (ushorts)
  unsigned aoffs[4], boffs[NWC];
#pragma unroll
  for (int g = 0; g < 4; ++g) aoffs[g] = (unsigned)((bm + g * 64 + srow) * AST + scol);
#pragma unroll
  for (int g = 0; g < NWC; ++g) boffs[g] = (unsigned)((bn + g * 64 + srow) * AST + scol);

  // read-side bases: low-6-bit field (kk*32 + quad*8) ^ sx; rows add >=bit6.
  const int basek0 = (quad * 8) ^ sx;
  const int basek1 = (32 + quad * 8) ^ sx;
  const int arow0 = (wr * (MR * 16) + fm) * 64;
  const int brow0 = (wc * 64 + fm) * 64;

  f32x4 acc[MR][4];
#pragma unroll
  for (int i = 0; i < MR; ++i)
#pragma unroll
    for (int j = 0; j < 4; ++j) acc[i][j] = (f32x4){0.f, 0.f, 0.f, 0.f};

  auto ka = [](int k0) { return (KLOG == 3072) ? (k0 < 2048 ? k0 : k0 - 2048) : k0; };
  auto kb = [](int k0) { return (KLOG == 3072) ? (k0 < 1024 ? k0 : k0 - 1024) : k0; };

  // prologue: tiles 0 and 1 in flight
  stageT<NWC>(A, BT, aoffs, boffs, As[0], Bs[0], ka(0), kb(0), w);
  stageT<NWC>(A, BT, aoffs, boffs, As[1], Bs[1], ka(64), kb(64), w);

#pragma unroll 1
  for (int t = 0; t < NKT; ++t) {
    const unsigned short* Ab = As[t & 1];
    const unsigned short* Bb = Bs[t & 1];
    unsigned short* Asb = As[t & 1];
    unsigned short* Bsb = Bs[t & 1];

    if (t < NKT - 1) {
      if constexpr (NWC == 4) asm volatile("s_waitcnt vmcnt(8)" ::: "memory");
      else                    asm volatile("s_waitcnt vmcnt(6)" ::: "memory");
    } else {
      asm volatile("s_waitcnt vmcnt(0)" ::: "memory");
    }
    __builtin_amdgcn_s_barrier();       // B0: tile t visible to all waves
    __builtin_amdgcn_sched_barrier(0);

    bf16x8 bfr[4][2];
    bf16x8 afr[2][2][2];  // [phase parity][row][kk]

    // initial reads: all B-frags + phase-0 A-frags (12 ds_read_b128)
#pragma unroll
    for (int j = 0; j < 4; ++j) {
      bfr[j][0] = *(const bf16x8*)&Bb[brow0 + j * 1024 + basek0];
      bfr[j][1] = *(const bf16x8*)&Bb[brow0 + j * 1024 + basek1];
    }
#pragma unroll
    for (int ii = 0; ii < 2; ++ii) {
      afr[0][ii][0] = *(const bf16x8*)&Ab[arow0 + ii * 1024 + basek0];
      afr[0][ii][1] = *(const bf16x8*)&Ab[arow0 + ii * 1024 + basek1];
    }
    __builtin_amdgcn_sched_barrier(0);

#pragma unroll
    for (int qq = 0; qq < NPH; ++qq) {
      if (qq + 1 < NPH) {
        // prefetch next phase's A-frags; they drain under this phase's MFMAs
#pragma unroll
        for (int ii = 0; ii < 2; ++ii) {
          afr[(qq + 1) & 1][ii][0] =
              *(const bf16x8*)&Ab[arow0 + ((qq + 1) * 2 + ii) * 1024 + basek0];
          afr[(qq + 1) & 1][ii][1] =
              *(const bf16x8*)&Ab[arow0 + ((qq + 1) * 2 + ii) * 1024 + basek1];
        }
        asm volatile("s_waitcnt lgkmcnt(4)" ::: "memory");  // current phase ready
      } else {
        asm volatile("s_waitcnt lgkmcnt(0)" ::: "memory");  // last phase: drain
      }
      __builtin_amdgcn_sched_barrier(0);  // rule #18: pin MFMA below the wait
      __builtin_amdgcn_s_setprio(1);
#pragma unroll
      for (int ii = 0; ii < 2; ++ii)
#pragma unroll
        for (int j = 0; j < 4; ++j) {
          acc[qq * 2 + ii][j] = __builtin_amdgcn_mfma_f32_16x16x32_bf16(
              afr[qq & 1][ii][0], bfr[j][0], acc[qq * 2 + ii][j], 0, 0, 0);
          acc[qq * 2 + ii][j] = __builtin_amdgcn_mfma_f32_16x16x32_bf16(
              afr[qq & 1][ii][1], bfr[j][1], acc[qq * 2 + ii][j], 0, 0, 0);
        }
      __builtin_amdgcn_s_setprio(0);
      __builtin_amdgcn_sched_barrier(0);
    }

    __builtin_amdgcn_s_barrier();       // B1: all waves done reading buf
    if (t + 2 < NKT) {
      const int k0 = (t + 2) * 64;
      stageT<NWC>(A, BT, aoffs, boffs, Asb, Bsb, ka(k0), kb(k0), w);
    }
  }

  if constexpr (EPI == 0) {
    float* C = (float*)(blockIdx.z ? C1 : C0);
#pragma unroll
    for (int i = 0; i < MR; ++i)
#pragma unroll
      for (int j = 0; j < 4; ++j) {
        size_t row = bm + wr * (MR * 16) + i * 16 + quad * 4;
        size_t col = bn + wc * 64 + j * 16 + fm;
        float bb = bias[col];
#pragma unroll
        for (int r = 0; r < 4; ++r) C[(row + r) * D + col] = acc[i][j][r] + bb;
      }
  } else {
    // softmax over this wave's 64 cols (= one full head), bf16 out
    unsigned short* HB = (unsigned short*)C0;
    const size_t head_col0 = bn + wc * 64;
    float bj[4];
#pragma unroll
    for (int j = 0; j < 4; ++j) bj[j] = bias[head_col0 + j * 16 + fm];
#pragma unroll
    for (int i = 0; i < MR; ++i) {
      f32x4 val[4];
#pragma unroll
      for (int j = 0; j < 4; ++j)
#pragma unroll
        for (int r = 0; r < 4; ++r) val[j][r] = (acc[i][j][r] + bj[j]) * 0.125f;

      f32x4 mx = val[0];
#pragma unroll
      for (int j = 1; j < 4; ++j)
#pragma unroll
        for (int r = 0; r < 4; ++r) mx[r] = fmaxf(mx[r], val[j][r]);
#pragma unroll
      for (int off = 1; off < 16; off <<= 1)
#pragma unroll
        for (int r = 0; r < 4; ++r) mx[r] = fmaxf(mx[r], __shfl_xor(mx[r], off, 64));

      f32x4 e[4];
      f32x4 sm = (f32x4){0.f, 0.f, 0.f, 0.f};
#pragma unroll
      for (int j = 0; j < 4; ++j)
#pragma unroll
        for (int r = 0; r < 4; ++r) {
          e[j][r] = __expf(val[j][r] - mx[r]);
          sm[r] += e[j][r];
        }
#pragma unroll
      for (int off = 1; off < 16; off <<= 1)
#pragma unroll
        for (int r = 0; r < 4; ++r) sm[r] += __shfl_xor(sm[r], off, 64);

      f32x4 inv;
#pragma unroll
      for (int r = 0; r < 4; ++r) inv[r] = 1.0f / sm[r];

#pragma unroll
      for (int j = 0; j < 4; ++j)
#pragma unroll
        for (int r = 0; r < 4; ++r) {
          size_t row = bm + wr * (MR * 16) + i * 16 + quad * 4 + r;
          HB[row * D + head_col0 + j * 16 + fm] = f2bf(e[j][r] * inv[r]);
        }
    }
  }
}

// ---------------------------------------------------------------------------
// M[b,h] = kh^T @ vh (64x64 per (b,h)), s-split 8-way with atomics.
// ---------------------------------------------------------------------------
__global__ __launch_bounds__(256) void compute_m_kernel(
    const float* __restrict__ KH, const float* __restrict__ VH, float* __restrict__ Mout) {
  const int sc = blockIdx.x, h = blockIdx.y, b = blockIdx.z;
  const int tid = threadIdx.x;
  const int i0 = (tid >> 4) * 4;
  const int j0 = (tid & 15) * 4;
  __shared__ float ks[16][64], vs[16][64];
  float acc[4][4];
#pragma unroll
  for (int a = 0; a < 4; a++)
#pragma unroll
    for (int c = 0; c < 4; c++) acc[a][c] = 0.f;

  const int s0 = sc * (S / 8);
  const int rr = tid >> 4;
  const int cc = (tid & 15) * 4;
  for (int s = s0; s < s0 + S / 8; s += 16) {
    size_t base = ((size_t)b * S + s + rr) * D + h * 64 + cc;
    __syncthreads();
    *(float4*)&ks[rr][cc] = *(const float4*)&KH[base];
    *(float4*)&vs[rr][cc] = *(const float4*)&VH[base];
    __syncthreads();
#pragma unroll
    for (int ss = 0; ss < 16; ss++) {
      float4 kf = *(const float4*)&ks[ss][i0];
      float4 vf = *(const float4*)&vs[ss][j0];
      float ka[4] = {kf.x, kf.y, kf.z, kf.w};
      float va[4] = {vf.x, vf.y, vf.z, vf.w};
#pragma unroll
      for (int a = 0; a < 4; a++)
#pragma unroll
        for (int c = 0; c < 4; c++) acc[a][c] += ka[a] * va[c];
    }
  }
  float* Mp = Mout + ((size_t)(b * H + h)) * DK * DK;
#pragma unroll
  for (int a = 0; a < 4; a++)
#pragma unroll
    for (int c = 0; c < 4; c++) atomicAdd(&Mp[(i0 + a) * DK + j0 + c], acc[a][c]);
}

// ---------------------------------------------------------------------------
// split_m_bias: M fp32 [bh][64k][64n] -> MSP bf16 [bh][2][64n][64k] (transposed
// hi,lo) AND BQM[bh][64 j] = sum_k bq[h,k]*M[k,j]  (unscaled).
// ---------------------------------------------------------------------------
__global__ __launch_bounds__(256) void split_m_bias_kernel(
    const float* __restrict__ M, const float* __restrict__ bq,
    unsigned short* __restrict__ MSP, float* __restrict__ BQM) {
  const int bh = blockIdx.x;
  const int h = bh & 15;
  const float* Mp = M + (size_t)bh * 4096;
  unsigned short* hiP = MSP + (size_t)bh * 8192;
  unsigned short* loP = hiP + 4096;
  for (int idx = threadIdx.x; idx < 4096; idx += 256) {
    int kk = idx >> 6, nn = idx & 63;
    unsigned short hi, lo;
    split2(Mp[idx], hi, lo);
    hiP[nn * 64 + kk] = hi;
    loP[nn * 64 + kk] = lo;
  }
  if (threadIdx.x < 64) {
    int j = threadIdx.x;
    float a = 0.f;
#pragma unroll 8
    for (int kk = 0; kk < 64; kk++) a += bq[h * 64 + kk] * Mp[kk * 64 + j];
    BQM[(size_t)bh * 64 + j] = a;
  }
}

// ---------------------------------------------------------------------------
// wqm: Wq'[b,h] = Wq[h] @ M[b,h]  (1024x64 per pair), 3-term split MFMA.
// A = WQA [h][1024 d][hi64|lo64]; B = MSP [bh][2][64 n][64 k] (transposed).
// Output WQM [b][n=h*64+j][d hi | 1024+d lo] (B^T layout for the qsm GEMM).
// grid (16, H, B); block = 64 d-rows; wave w owns d-rows [c*64+w*16, +16).
// ---------------------------------------------------------------------------
__global__ __launch_bounds__(256) void wqm_kernel(
    const unsigned short* __restrict__ WQA, const unsigned short* __restrict__ MSP,
    unsigned short* __restrict__ WQM) {
  const int c = blockIdx.x, h = blockIdx.y, b = blockIdx.z;
  const int tid = threadIdx.x;
  const int lane = tid & 63;
  const int w = tid >> 6;
  const int fm = lane & 15;
  const int quad = lane >> 4;
  const int ko = quad * 8;
  const int dbase = c * 64 + w * 16;

  const unsigned short* arow = WQA + ((size_t)h * 1024 + dbase + fm) * 128;
  bf16x8 ahi0 = *(const bf16x8*)&arow[ko];        // k 0..31 hi
  bf16x8 ahi1 = *(const bf16x8*)&arow[32 + ko];   // k 32..63 hi
  bf16x8 alo0 = *(const bf16x8*)&arow[64 + ko];   // k 0..31 lo
  bf16x8 alo1 = *(const bf16x8*)&arow[96 + ko];   // k 32..63 lo

  const unsigned short* hiP = MSP + ((size_t)(b * H + h)) * 8192;
  const unsigned short* loP = hiP + 4096;
  f32x4 acc[4];
#pragma unroll
  for (int j = 0; j < 4; j++) acc[j] = (f32x4){0.f, 0.f, 0.f, 0.f};
#pragma unroll
  for (int j = 0; j < 4; j++) {
    bf16x8 bhi0 = *(const bf16x8*)&hiP[(j * 16 + fm) * 64 + ko];
    bf16x8 bhi1 = *(const bf16x8*)&hiP[(j * 16 + fm) * 64 + 32 + ko];
    bf16x8 blo0 = *(const bf16x8*)&loP[(j * 16 + fm) * 64 + ko];
    bf16x8 blo1 = *(const bf16x8*)&loP[(j * 16 + fm) * 64 + 32 + ko];
    acc[j] = __builtin_amdgcn_mfma_f32_16x16x32_bf16(ahi0, bhi0, acc[j], 0, 0, 0);
    acc[j] = __builtin_amdgcn_mfma_f32_16x16x32_bf16(ahi1, bhi1, acc[j], 0, 0, 0);
    acc[j] = __builtin_amdgcn_mfma_f32_16x16x32_bf16(alo0, bhi0, acc[j], 0, 0, 0);
    acc[j] = __builtin_amdgcn_mfma_f32_16x16x32_bf16(alo1, bhi1, acc[j], 0, 0, 0);
    acc[j] = __builtin_amdgcn_mfma_f32_16x16x32_bf16(ahi0, blo0, acc[j], 0, 0, 0);
    acc[j] = __builtin_amdgcn_mfma_f32_16x16x32_bf16(ahi1, blo1, acc[j], 0, 0, 0);
  }

  // C[d=dbase+quad*4+r][col j*16+fm]; write split to WQM[b][h*64+col][d]
#pragma unroll
  for (int j = 0; j < 4; j++) {
    int n = h * 64 + j * 16 + fm;
    ushort4 hv, lv;
    unsigned short hi, lo;
    split2(acc[j][0], hi, lo); hv.x = hi; lv.x = lo;
    split2(acc[j][1], hi, lo); hv.y = hi; lv.y = lo;
    split2(acc[j][2], hi, lo); hv.z = hi; lv.z = lo;
    split2(acc[j][3], hi, lo); hv.w = hi; lv.w = lo;
    size_t base = ((size_t)b * D + n) * GKA + dbase + quad * 4;
    *(ushort4*)&WQM[base] = hv;
    *(ushort4*)&WQM[base + 1024] = lv;
  }
}

// ---------------------------------------------------------------------------
extern "C" void kernel_launch(void* const* d_in, const int* in_sizes, int n_in,
                              void* d_out, int out_size, void* d_ws, size_t ws_size,
                              hipStream_t stream) {
  const float* q = (const float*)d_in[0];
  const float* k = (const float*)d_in[1];
  const float* v = (const float*)d_in[2];
  const float* wq_w = (const float*)d_in[3];
  const float* wq_b = (const float*)d_in[4];
  const float* wk_w = (const float*)d_in[5];
  const float* wk_b = (const float*)d_in[6];
  const float* wv_w = (const float*)d_in[7];
  const float* wv_b = (const float*)d_in[8];
  const float* wo_w = (const float*)d_in[9];
  const float* wo_b = (const float*)d_in[10];
  float* out = (float*)d_out;

  // ws (143 MB): KSP 32 (->HB 16 | WQM 16) | VSP 32 (->MSP 1 + BQM) | QSP 32 |
  //              VH 32 | M 1 | WKS 4 | WVS 4 | WQA 4 | WOB 2.   KH lives in d_out.
  unsigned short* KSP = (unsigned short*)d_ws;
  unsigned short* VSP = KSP + (size_t)16 * 1024 * 1024;
  unsigned short* QSP = VSP + (size_t)16 * 1024 * 1024;
  float* VH = (float*)(QSP + (size_t)16 * 1024 * 1024);
  float* M = VH + (size_t)MS * D;
  unsigned short* WKS = (unsigned short*)(M + 256 * 1024);
  unsigned short* WVS = WKS + (size_t)2 * 1024 * 1024;
  unsigned short* WQA = WVS + (size_t)2 * 1024 * 1024;
  unsigned short* WOB = WQA + (size_t)2 * 1024 * 1024;
  // aliases
  float* KH = out;                                   // dead after compute_m
  unsigned short* HB = KSP;                          // KSP dead after gemm KV
  unsigned short* WQM = KSP + (size_t)8 * 1024 * 1024;
  unsigned short* MSP = VSP;                         // VSP dead after gemm KV
  float* BQM = (float*)(VSP + 512 * 1024);

  dim3 blk(256);

  prep_kernel<<<38144, blk, 0, stream>>>(q, k, v, wk_w, wv_w, wq_w, wo_w,
                                         KSP, VSP, QSP, WKS, WVS, WQA, WOB, M);
  // K/V projections: 256x256 tiles, split-Markidis K=3072
  gemm256<4, 0, 3072><<<dim3(4, 32, 2), dim3(512), 0, stream>>>(
      KSP, VSP, WKS, WVS, wk_b, wv_b, KH, VH);
  compute_m_kernel<<<dim3(8, H, B), blk, 0, stream>>>(KH, VH, M);
  split_m_bias_kernel<<<64, blk, 0, stream>>>(M, wq_b, MSP, BQM);
  wqm_kernel<<<dim3(16, H, B), blk, 0, stream>>>(WQA, MSP, WQM);
  // fused logit GEMM + softmax: 256x128 tiles (full 256-block grid)
  gemm256<2, 1, 3072><<<dim3(8, 32, 1), dim3(512), 0, stream>>>(
      QSP, nullptr, WQM, nullptr, BQM, nullptr, HB, nullptr);
  // output projection: plain bf16, K=1024, 256x128 tiles
  gemm256<2, 0, 1024><<<dim3(8, 32, 1), dim3(512), 0, stream>>>(
      HB, HB, WOB, WOB, wo_b, wo_b, out, out);
}